// Round 6
// baseline (2230.631 us; speedup 1.0000x reference)
//
#include <hip/hip_runtime.h>
#include <hip/hip_bf16.h>
#include <math.h>

#define GN 19            // graph nodes
#define BB 256
#define TT 256

typedef short short8 __attribute__((ext_vector_type(8)));
typedef float f4 __attribute__((ext_vector_type(4)));

union Frag { int i[4]; short8 s; };

// wave-local LDS ordering fence: wait LDS ops, NO vmcnt drain, no barrier.
#define LWAIT() __asm__ volatile("s_waitcnt lgkmcnt(0)" ::: "memory")
// workgroup barrier WITHOUT vmcnt(0) drain: global loads/stores stay in flight.
#define WGBAR() __asm__ volatile("s_waitcnt lgkmcnt(0)\ns_barrier" ::: "memory")

// packed RNE float pair -> bf16 pair (v_cvt_pk_bf16_f32 on gfx950)
__device__ __forceinline__ int pkbf(float a, float b) {
    __hip_bfloat162 h2 = __float22bfloat162_rn(make_float2(a, b));
    union { __hip_bfloat162 h; int i; } u; u.h = h2; return u.i;
}

__device__ __forceinline__ float rl(float v, int j) {
    return __int_as_float(__builtin_amdgcn_readlane(__float_as_int(v), j));
}
__device__ __forceinline__ float fexp2(float x) { return __builtin_amdgcn_exp2f(x); }
__device__ __forceinline__ float frcp(float x)  { return __builtin_amdgcn_rcpf(x); }
__device__ __forceinline__ float sigm(float x)  { return frcp(1.f + fexp2(-1.4426950408889634f * x)); }
__device__ __forceinline__ float tanha(float x) { float e = fexp2(2.8853900817779268f * x); return 1.f - 2.f * frcp(e + 1.f); }

// ---------------------------------------------------------------------------
// Kernel A: graph encoder via bf16 MFMA (16x16x32).  One wave per block,
// grid-stride over graphs.  1-wave workgroup => no s_barrier needed at all;
// phase ordering via lgkmcnt waits only (global loads stay in flight).
// Next graph's A is register-prefetched during the current graph's pipeline.
// ---------------------------------------------------------------------------
__global__ __launch_bounds__(64) void encoder_mfma(
    const float* __restrict__ conn,   // (G,19,19)
    const int*   __restrict__ mask,   // (G)
    const float* __restrict__ w1_w,   // (64,19)
    const float* __restrict__ w1_b,   // (64)
    const float* __restrict__ w2_w,   // (64,64)
    const float* __restrict__ w2_b,   // (64)
    float* __restrict__ emb,          // (G,64)
    int num_graphs)
{
    __shared__ float S[2304];         // 9216 B, reused 4 ways
    __shared__ float dis[32];
    __shared__ float ps[256];

    const int t = threadIdx.x;
    const int l15 = t & 15;
    const int quad = t >> 4;

    // k-validity mask for B-operand repacks (k = quad*8+j < 19)
    float km[8];
    #pragma unroll
    for (int j = 0; j < 8; ++j) km[j] = (quad * 8 + j < GN) ? 1.f : 0.f;

    // loop-invariant scatter coords for A staging (e = t + 64*i)
    int rr[6], cc[6];
    #pragma unroll
    for (int i = 0; i < 6; ++i) {
        int e = t + 64 * i;
        rr[i] = e / GN;
        cc[i] = e - rr[i] * GN;
    }

    // ---- weight fragments + biases (once per block) ----
    Frag w1F[4];
    #pragma unroll
    for (int nt = 0; nt < 4; ++nt) {
        int n = nt * 16 + l15;
        #pragma unroll
        for (int p = 0; p < 4; ++p) {
            int k0 = quad * 8 + 2 * p, k1 = k0 + 1;
            float a = (k0 < GN) ? w1_w[n * GN + k0] : 0.f;
            float b = (k1 < GN) ? w1_w[n * GN + k1] : 0.f;
            w1F[nt].i[p] = pkbf(a, b);
        }
    }
    Frag w2F[2][4];
    #pragma unroll
    for (int kt = 0; kt < 2; ++kt)
        #pragma unroll
        for (int nt = 0; nt < 4; ++nt) {
            int n = nt * 16 + l15;
            #pragma unroll
            for (int p = 0; p < 4; ++p) {
                int k = kt * 32 + quad * 8 + 2 * p;
                w2F[kt][nt].i[p] = pkbf(w2_w[n * 64 + k], w2_w[n * 64 + k + 1]);
            }
        }
    float b1v[4], b2v[4];
    #pragma unroll
    for (int nt = 0; nt < 4; ++nt) {
        b1v[nt] = w1_b[nt * 16 + l15];
        b2v[nt] = w2_b[nt * 16 + l15];
    }

    // prologue: prefetch first graph's A into registers
    float pf[6];
    {
        int g0 = blockIdx.x < num_graphs ? blockIdx.x : 0;
        const float* Ag = conn + (size_t)g0 * (GN * GN);
        #pragma unroll
        for (int i = 0; i < 6; ++i) {
            int e = t + 64 * i;
            if (e < GN * GN) pf[i] = Ag[e];
        }
    }

    #pragma unroll 1
    for (int g = blockIdx.x; g < num_graphs; g += gridDim.x) {
        // zero A region: rows 0..31, cols 0..31 (stride 68)
        #pragma unroll
        for (int i = 0; i < 4; ++i) {
            int s = t + 64 * i;          // 256 float4 slots
            int row = s >> 3, c4 = s & 7;
            f4 z = {0.f, 0.f, 0.f, 0.f};
            *(f4*)&S[row * 68 + c4 * 4] = z;
        }
        LWAIT();   // zeros before scatter (same addresses)
        // scatter prefetched A (361 floats)
        #pragma unroll
        for (int i = 0; i < 6; ++i) {
            if (t + 64 * i < GN * GN) S[rr[i] * 68 + cc[i]] = pf[i];
        }
        // issue prefetch for the NEXT graph (stays in flight all pipeline)
        {
            int gn = g + gridDim.x;
            const float* Ag = conn + (size_t)(gn < num_graphs ? gn : g) * (GN * GN);
            #pragma unroll
            for (int i = 0; i < 6; ++i) {
                int e = t + 64 * i;
                if (e < GN * GN) pf[i] = Ag[e];
            }
        }
        LWAIT();   // staging visible

        // degree -> dis (lanes 0..18), zero pad 19..31
        if (t < 32) {
            float dv = 0.f;
            if (t < GN) {
                float d = 1.0f;   // self loop
                #pragma unroll
                for (int c4 = 0; c4 < 8; ++c4) {
                    f4 v = *(f4*)&S[t * 68 + c4 * 4];
                    d += v.x + v.y + v.z + v.w;
                }
                dv = rsqrtf(d);
            }
            dis[t] = dv;
        }
        LWAIT();

        // pack aF (raw A) and anF (normalized adjacency), 2 M-tiles
        float dk[8];
        {
            f4 v0 = *(f4*)&dis[quad * 8];
            f4 v1 = *(f4*)&dis[quad * 8 + 4];
            dk[0]=v0.x; dk[1]=v0.y; dk[2]=v0.z; dk[3]=v0.w;
            dk[4]=v1.x; dk[5]=v1.y; dk[6]=v1.z; dk[7]=v1.w;
        }
        Frag aF[2], anF[2];
        #pragma unroll
        for (int mt = 0; mt < 2; ++mt) {
            int m = l15 + 16 * mt;
            float dm = dis[m];
            f4 v0 = *(f4*)&S[m * 68 + quad * 8];
            f4 v1 = *(f4*)&S[m * 68 + quad * 8 + 4];
            float av[8] = {v0.x, v0.y, v0.z, v0.w, v1.x, v1.y, v1.z, v1.w};
            float an[8];
            #pragma unroll
            for (int j = 0; j < 8; ++j) {
                int k = quad * 8 + j;
                an[j] = (av[j] + (m == k ? 1.f : 0.f)) * dm * dk[j];
            }
            #pragma unroll
            for (int p = 0; p < 4; ++p) {
                aF[mt].i[p]  = pkbf(av[2*p], av[2*p+1]);
                anF[mt].i[p] = pkbf(an[2*p], an[2*p+1]);
            }
        }
        LWAIT();   // A reads done before H1^T overwrites S

        // MFMA1: H1 = A @ W1^T + b1  -> S transposed (S[n*36 + k])
        #pragma unroll
        for (int mt = 0; mt < 2; ++mt)
            #pragma unroll
            for (int nt = 0; nt < 4; ++nt) {
                float bb = b1v[nt];
                f4 c = {bb, bb, bb, bb};
                c = __builtin_amdgcn_mfma_f32_16x16x32_bf16(aF[mt].s, w1F[nt].s, c, 0, 0, 0);
                int col = nt * 16 + l15;
                #pragma unroll
                for (int r = 0; r < 4; ++r)
                    S[col * 36 + (mt * 16 + quad * 4 + r)] = c[r];
            }
        LWAIT();

        // pack H1 as B-op: 2 x b128 per n-tile, mask k>=19
        Frag hF[4];
        #pragma unroll
        for (int nt = 0; nt < 4; ++nt) {
            int n = nt * 16 + l15;
            f4 v0 = *(f4*)&S[n * 36 + quad * 8];
            f4 v1 = *(f4*)&S[n * 36 + quad * 8 + 4];
            float vv[8] = {v0.x, v0.y, v0.z, v0.w, v1.x, v1.y, v1.z, v1.w};
            #pragma unroll
            for (int p = 0; p < 4; ++p)
                hF[nt].i[p] = pkbf(vv[2*p] * km[2*p], vv[2*p+1] * km[2*p+1]);
        }
        LWAIT();   // H1^T reads done

        // MFMA2: X1 = relu(An @ H1) -> S row-major (rows>=19 naturally zero)
        #pragma unroll
        for (int mt = 0; mt < 2; ++mt)
            #pragma unroll
            for (int nt = 0; nt < 4; ++nt) {
                f4 c = {0.f, 0.f, 0.f, 0.f};
                c = __builtin_amdgcn_mfma_f32_16x16x32_bf16(anF[mt].s, hF[nt].s, c, 0, 0, 0);
                int col = nt * 16 + l15;
                #pragma unroll
                for (int r = 0; r < 4; ++r)
                    S[(mt * 16 + quad * 4 + r) * 68 + col] = fmaxf(c[r], 0.f);
            }
        LWAIT();

        // pack X1 as A-op (2 b128 per (mt,kt))
        Frag xF[2][2];
        #pragma unroll
        for (int mt = 0; mt < 2; ++mt) {
            int m = l15 + 16 * mt;
            #pragma unroll
            for (int kt = 0; kt < 2; ++kt) {
                f4 v0 = *(f4*)&S[m * 68 + kt * 32 + quad * 8];
                f4 v1 = *(f4*)&S[m * 68 + kt * 32 + quad * 8 + 4];
                xF[mt][kt].i[0] = pkbf(v0.x, v0.y);
                xF[mt][kt].i[1] = pkbf(v0.z, v0.w);
                xF[mt][kt].i[2] = pkbf(v1.x, v1.y);
                xF[mt][kt].i[3] = pkbf(v1.z, v1.w);
            }
        }
        LWAIT();   // X1 reads done

        // MFMA3: H2 = X1 @ W2^T + b2 -> S transposed
        #pragma unroll
        for (int mt = 0; mt < 2; ++mt)
            #pragma unroll
            for (int nt = 0; nt < 4; ++nt) {
                float bb = b2v[nt];
                f4 c = {bb, bb, bb, bb};
                c = __builtin_amdgcn_mfma_f32_16x16x32_bf16(xF[mt][0].s, w2F[0][nt].s, c, 0, 0, 0);
                c = __builtin_amdgcn_mfma_f32_16x16x32_bf16(xF[mt][1].s, w2F[1][nt].s, c, 0, 0, 0);
                int col = nt * 16 + l15;
                #pragma unroll
                for (int r = 0; r < 4; ++r)
                    S[col * 36 + (mt * 16 + quad * 4 + r)] = c[r];
            }
        LWAIT();

        // pack H2 as B-op
        #pragma unroll
        for (int nt = 0; nt < 4; ++nt) {
            int n = nt * 16 + l15;
            f4 v0 = *(f4*)&S[n * 36 + quad * 8];
            f4 v1 = *(f4*)&S[n * 36 + quad * 8 + 4];
            float vv[8] = {v0.x, v0.y, v0.z, v0.w, v1.x, v1.y, v1.z, v1.w};
            #pragma unroll
            for (int p = 0; p < 4; ++p)
                hF[nt].i[p] = pkbf(vv[2*p] * km[2*p], vv[2*p+1] * km[2*p+1]);
        }

        // MFMA4: X2 = relu(An @ H2); column sums -> emb mean
        float cs[4];
        #pragma unroll
        for (int nt = 0; nt < 4; ++nt) cs[nt] = 0.f;
        #pragma unroll
        for (int mt = 0; mt < 2; ++mt)
            #pragma unroll
            for (int nt = 0; nt < 4; ++nt) {
                f4 c = {0.f, 0.f, 0.f, 0.f};
                c = __builtin_amdgcn_mfma_f32_16x16x32_bf16(anF[mt].s, hF[nt].s, c, 0, 0, 0);
                if (mt == 0) {
                    cs[nt] += fmaxf(c[0], 0.f) + fmaxf(c[1], 0.f)
                            + fmaxf(c[2], 0.f) + fmaxf(c[3], 0.f);
                } else if (quad == 0) {   // rows 16,17,18 valid
                    cs[nt] += fmaxf(c[0], 0.f) + fmaxf(c[1], 0.f) + fmaxf(c[2], 0.f);
                }
            }
        #pragma unroll
        for (int nt = 0; nt < 4; ++nt)
            ps[quad * 64 + nt * 16 + l15] = cs[nt];
        LWAIT();
        float tot = ps[t] + ps[64 + t] + ps[128 + t] + ps[192 + t];
        float mf = (float)mask[g];
        emb[(size_t)g * 64 + t] = tot * (1.f / 19.f) * mf;
        LWAIT();   // ps reads done before next iteration reuses LDS
    }
}

// ---------------------------------------------------------------------------
// Kernel B: LSTM layer 0.  One block (4 waves) per batch element; thread tid
// owns gate-row tid.  Raw s_barrier (no vmcnt drain).  2-deep ping-pong
// x-row prefetch (row t+2 issued at step t => load window >= 1 full step,
// covering HBM latency).  Step order after barrier: gate ds_reads issued,
// then x-FMAs (independent, hide ds_read latency), then activations.
// ---------------------------------------------------------------------------
__global__ __launch_bounds__(256, 1) void lstm_l0(
    const float* __restrict__ x,      // (B*T, 64)
    const float* __restrict__ Wih, const float* __restrict__ Whh,
    const float* __restrict__ bih, const float* __restrict__ bhh,
    float* __restrict__ hseq)         // (B*T, 64)
{
    __shared__ float gs[2][256];
    const int tid = threadIdx.x;
    const int w = tid >> 6, l = tid & 63;
    const int b = blockIdx.x;

    float wi[64], wh[64];
    {
        const float4* p = (const float4*)(Wih + tid * 64);
        const float4* q = (const float4*)(Whh + tid * 64);
        #pragma unroll
        for (int j = 0; j < 16; ++j) {
            ((float4*)wi)[j] = p[j];
            ((float4*)wh)[j] = q[j];
        }
    }
    const float bias = bih[tid] + bhh[tid];
    const float* __restrict__ xb = x + (size_t)b * TT * 64;

    // prologue: xc for step 0 (direct), buf[1] <- row 1
    float xc;
    {
        float n0 = 0.f, n1 = 0.f, n2 = 0.f, n3 = 0.f;
        #pragma unroll
        for (int j = 0; j < 64; j += 4) {
            n0 = fmaf(xb[j],     wi[j],     n0);
            n1 = fmaf(xb[j + 1], wi[j + 1], n1);
            n2 = fmaf(xb[j + 2], wi[j + 2], n2);
            n3 = fmaf(xb[j + 3], wi[j + 3], n3);
        }
        xc = (n0 + n1) + (n2 + n3);
    }
    f4 buf[2][16];
    {
        const f4* __restrict__ r1 = (const f4*)(xb + 64);
        #pragma unroll
        for (int k = 0; k < 16; ++k) buf[1][k] = r1[k];
    }

    float h = 0.f, c = 0.f;

    #pragma unroll 1
    for (int t = 0; t < TT; ++t) {
        // issue loads for row t+2 into buf[t&1] (consumed at iter t+1)
        {
            int rowi = t + 2 < TT ? t + 2 : TT - 1;
            const f4* __restrict__ rp = (const f4*)(xb + rowi * 64);
            #pragma unroll
            for (int k = 0; k < 16; ++k) buf[t & 1][k] = rp[k];
        }

        // h-part (recurrent critical path)
        float a0 = bias + xc, a1 = 0.f, a2 = 0.f, a3 = 0.f;
        #pragma unroll
        for (int j = 0; j < 64; j += 4) {
            a0 = fmaf(rl(h, j),     wh[j],     a0);
            a1 = fmaf(rl(h, j + 1), wh[j + 1], a1);
            a2 = fmaf(rl(h, j + 2), wh[j + 2], a2);
            a3 = fmaf(rl(h, j + 3), wh[j + 3], a3);
        }
        gs[t & 1][tid] = (a0 + a1) + (a2 + a3);
        WGBAR();

        // issue gate reads first ...
        const float* gp = gs[t & 1];
        float gi = gp[l], gf = gp[64 + l], gg = gp[128 + l], go = gp[192 + l];

        // ... x-FMAs for step t+1 fill the ds_read latency window
        float n0 = 0.f, n1 = 0.f, n2 = 0.f, n3 = 0.f;
        #pragma unroll
        for (int k = 0; k < 16; ++k) {
            f4 v = buf[(t + 1) & 1][k];   // row t+1, loaded since iter t-1
            n0 = fmaf(v.x, wi[4*k],     n0);
            n1 = fmaf(v.y, wi[4*k + 1], n1);
            n2 = fmaf(v.z, wi[4*k + 2], n2);
            n3 = fmaf(v.w, wi[4*k + 3], n3);
        }
        float xcn = (n0 + n1) + (n2 + n3);

        // activations (step t)
        c = sigm(gf) * c + sigm(gi) * tanha(gg);
        h = sigm(go) * tanha(c);
        if (w == 0) hseq[((size_t)b * TT + t) * 64 + l] = h;
        xc = xcn;
    }
}

// ---------------------------------------------------------------------------
// Kernel C: LSTM layer 1 + FC head.  Same pipeline; captures h at last_idx.
// ---------------------------------------------------------------------------
__global__ __launch_bounds__(256, 1) void lstm_l1_head(
    const float* __restrict__ x,      // (B*T, 64) = h0seq
    const int*   __restrict__ mask,   // (B, T)
    const float* __restrict__ Wih, const float* __restrict__ Whh,
    const float* __restrict__ bih, const float* __restrict__ bhh,
    const float* __restrict__ fc1_w, const float* __restrict__ fc1_b,
    const float* __restrict__ fc2_w, const float* __restrict__ fc2_b,
    float* __restrict__ out)          // (B, 2)
{
    __shared__ float gs[2][256];
    __shared__ int li_s;
    const int tid = threadIdx.x;
    const int w = tid >> 6, l = tid & 63;
    const int b = blockIdx.x;

    float wi[64], wh[64];
    {
        const float4* p = (const float4*)(Wih + tid * 64);
        const float4* q = (const float4*)(Whh + tid * 64);
        #pragma unroll
        for (int j = 0; j < 16; ++j) {
            ((float4*)wi)[j] = p[j];
            ((float4*)wh)[j] = q[j];
        }
    }
    const float bias = bih[tid] + bhh[tid];

    // last_idx = clip(sum(mask)-1, 0, T-1)
    gs[0][tid] = (float)mask[b * TT + tid];
    __syncthreads();
    if (tid == 0) {
        float s = 0.f;
        for (int t = 0; t < TT; ++t) s += gs[0][t];
        int li = (int)s - 1;
        li = li < 0 ? 0 : (li > TT - 1 ? TT - 1 : li);
        li_s = li;
    }
    __syncthreads();
    const int lastidx = li_s;

    const float* __restrict__ xb = x + (size_t)b * TT * 64;

    float xc;
    {
        float n0 = 0.f, n1 = 0.f, n2 = 0.f, n3 = 0.f;
        #pragma unroll
        for (int j = 0; j < 64; j += 4) {
            n0 = fmaf(xb[j],     wi[j],     n0);
            n1 = fmaf(xb[j + 1], wi[j + 1], n1);
            n2 = fmaf(xb[j + 2], wi[j + 2], n2);
            n3 = fmaf(xb[j + 3], wi[j + 3], n3);
        }
        xc = (n0 + n1) + (n2 + n3);
    }
    f4 buf[2][16];
    {
        const f4* __restrict__ r1 = (const f4*)(xb + 64);
        #pragma unroll
        for (int k = 0; k < 16; ++k) buf[1][k] = r1[k];
    }

    float h = 0.f, c = 0.f, hl = 0.f;

    #pragma unroll 1
    for (int t = 0; t < TT; ++t) {
        {
            int rowi = t + 2 < TT ? t + 2 : TT - 1;
            const f4* __restrict__ rp = (const f4*)(xb + rowi * 64);
            #pragma unroll
            for (int k = 0; k < 16; ++k) buf[t & 1][k] = rp[k];
        }

        float a0 = bias + xc, a1 = 0.f, a2 = 0.f, a3 = 0.f;
        #pragma unroll
        for (int j = 0; j < 64; j += 4) {
            a0 = fmaf(rl(h, j),     wh[j],     a0);
            a1 = fmaf(rl(h, j + 1), wh[j + 1], a1);
            a2 = fmaf(rl(h, j + 2), wh[j + 2], a2);
            a3 = fmaf(rl(h, j + 3), wh[j + 3], a3);
        }
        gs[t & 1][tid] = (a0 + a1) + (a2 + a3);
        WGBAR();

        const float* gp = gs[t & 1];
        float gi = gp[l], gf = gp[64 + l], gg = gp[128 + l], go = gp[192 + l];

        float n0 = 0.f, n1 = 0.f, n2 = 0.f, n3 = 0.f;
        #pragma unroll
        for (int k = 0; k < 16; ++k) {
            f4 v = buf[(t + 1) & 1][k];
            n0 = fmaf(v.x, wi[4*k],     n0);
            n1 = fmaf(v.y, wi[4*k + 1], n1);
            n2 = fmaf(v.z, wi[4*k + 2], n2);
            n3 = fmaf(v.w, wi[4*k + 3], n3);
        }
        float xcn = (n0 + n1) + (n2 + n3);

        c = sigm(gf) * c + sigm(gi) * tanha(gg);
        h = sigm(go) * tanha(c);
        if (t == lastidx) hl = h;
        xc = xcn;
    }

    // head: fc1 (64->32) relu, fc2 (32->2); wave 0 only
    __syncthreads();
    if (w == 0 && l < 32) {
        float acc = fc1_b[l];
        const float* fw = fc1_w + l * 64;
        #pragma unroll
        for (int j = 0; j < 64; ++j)
            acc = fmaf(fw[j], rl(hl, j), acc);
        gs[0][l] = fmaxf(acc, 0.f);
    }
    __syncthreads();
    if (w == 0 && l < 2) {
        float acc = fc2_b[l];
        #pragma unroll
        for (int j = 0; j < 32; ++j)
            acc = fmaf(fc2_w[l * 32 + j], gs[0][j], acc);
        out[b * 2 + l] = acc;
    }
}

// ---------------------------------------------------------------------------
extern "C" void kernel_launch(void* const* d_in, const int* in_sizes, int n_in,
                              void* d_out, int out_size, void* d_ws, size_t ws_size,
                              hipStream_t stream)
{
    const float* conn  = (const float*)d_in[0];
    const int*   mask  = (const int*)  d_in[1];
    const float* w1_w  = (const float*)d_in[2];
    const float* w1_b  = (const float*)d_in[3];
    const float* w2_w  = (const float*)d_in[4];
    const float* w2_b  = (const float*)d_in[5];
    const float* Wih0  = (const float*)d_in[6];
    const float* Whh0  = (const float*)d_in[7];
    const float* bih0  = (const float*)d_in[8];
    const float* bhh0  = (const float*)d_in[9];
    const float* Wih1  = (const float*)d_in[10];
    const float* Whh1  = (const float*)d_in[11];
    const float* bih1  = (const float*)d_in[12];
    const float* bhh1  = (const float*)d_in[13];
    const float* fc1_w = (const float*)d_in[14];
    const float* fc1_b = (const float*)d_in[15];
    const float* fc2_w = (const float*)d_in[16];
    const float* fc2_b = (const float*)d_in[17];

    float* out = (float*)d_out;
    float* emb   = (float*)d_ws;                         // 16.8 MB
    float* h0seq = (float*)d_ws + (size_t)BB * TT * 64;  // +16.8 MB

    const int num_graphs = BB * TT;

    encoder_mfma<<<8192, 64, 0, stream>>>(
        conn, mask, w1_w, w1_b, w2_w, w2_b, emb, num_graphs);

    lstm_l0<<<BB, 256, 0, stream>>>(emb, Wih0, Whh0, bih0, bhh0, h0seq);

    lstm_l1_head<<<BB, 256, 0, stream>>>(
        h0seq, mask, Wih1, Whh1, bih1, bhh1,
        fc1_w, fc1_b, fc2_w, fc2_b, out);
}

// Round 7
// 773.983 us; speedup vs baseline: 2.8820x; 2.8820x over previous
//
#include <hip/hip_runtime.h>
#include <hip/hip_bf16.h>
#include <math.h>

#define GN 19            // graph nodes
#define BB 256
#define TT 256

typedef short short8 __attribute__((ext_vector_type(8)));
typedef float f4 __attribute__((ext_vector_type(4)));

union Frag { int i[4]; short8 s; };

// wave-local LDS ordering fence: wait LDS ops, NO vmcnt drain, no barrier.
#define LWAIT() __asm__ volatile("s_waitcnt lgkmcnt(0)" ::: "memory")
// workgroup barrier WITHOUT vmcnt(0) drain: global loads/stores stay in flight.
#define WGBAR() __asm__ volatile("s_waitcnt lgkmcnt(0)\ns_barrier" ::: "memory")

// packed RNE float pair -> bf16 pair (v_cvt_pk_bf16_f32 on gfx950)
__device__ __forceinline__ int pkbf(float a, float b) {
    __hip_bfloat162 h2 = __float22bfloat162_rn(make_float2(a, b));
    union { __hip_bfloat162 h; int i; } u; u.h = h2; return u.i;
}

__device__ __forceinline__ float rl(float v, int j) {
    return __int_as_float(__builtin_amdgcn_readlane(__float_as_int(v), j));
}
__device__ __forceinline__ float fexp2(float x) { return __builtin_amdgcn_exp2f(x); }
__device__ __forceinline__ float frcp(float x)  { return __builtin_amdgcn_rcpf(x); }
__device__ __forceinline__ float sigm(float x)  { return frcp(1.f + fexp2(-1.4426950408889634f * x)); }
__device__ __forceinline__ float tanha(float x) { float e = fexp2(2.8853900817779268f * x); return 1.f - 2.f * frcp(e + 1.f); }

// ---------------------------------------------------------------------------
// Kernel A: graph encoder via bf16 MFMA (16x16x32).  One wave per block,
// grid-stride over graphs.  1-wave workgroup => no s_barrier needed at all;
// phase ordering via lgkmcnt waits only (global loads stay in flight).
// Next graph's A is register-prefetched during the current graph's pipeline.
// ---------------------------------------------------------------------------
__global__ __launch_bounds__(64) void encoder_mfma(
    const float* __restrict__ conn,   // (G,19,19)
    const int*   __restrict__ mask,   // (G)
    const float* __restrict__ w1_w,   // (64,19)
    const float* __restrict__ w1_b,   // (64)
    const float* __restrict__ w2_w,   // (64,64)
    const float* __restrict__ w2_b,   // (64)
    float* __restrict__ emb,          // (G,64)
    int num_graphs)
{
    __shared__ float S[2304];         // 9216 B, reused 4 ways
    __shared__ float dis[32];
    __shared__ float ps[256];

    const int t = threadIdx.x;
    const int l15 = t & 15;
    const int quad = t >> 4;

    // k-validity mask for B-operand repacks (k = quad*8+j < 19)
    float km[8];
    #pragma unroll
    for (int j = 0; j < 8; ++j) km[j] = (quad * 8 + j < GN) ? 1.f : 0.f;

    // loop-invariant scatter coords for A staging (e = t + 64*i)
    int rr[6], cc[6];
    #pragma unroll
    for (int i = 0; i < 6; ++i) {
        int e = t + 64 * i;
        rr[i] = e / GN;
        cc[i] = e - rr[i] * GN;
    }

    // ---- weight fragments + biases (once per block) ----
    Frag w1F[4];
    #pragma unroll
    for (int nt = 0; nt < 4; ++nt) {
        int n = nt * 16 + l15;
        #pragma unroll
        for (int p = 0; p < 4; ++p) {
            int k0 = quad * 8 + 2 * p, k1 = k0 + 1;
            float a = (k0 < GN) ? w1_w[n * GN + k0] : 0.f;
            float b = (k1 < GN) ? w1_w[n * GN + k1] : 0.f;
            w1F[nt].i[p] = pkbf(a, b);
        }
    }
    Frag w2F[2][4];
    #pragma unroll
    for (int kt = 0; kt < 2; ++kt)
        #pragma unroll
        for (int nt = 0; nt < 4; ++nt) {
            int n = nt * 16 + l15;
            #pragma unroll
            for (int p = 0; p < 4; ++p) {
                int k = kt * 32 + quad * 8 + 2 * p;
                w2F[kt][nt].i[p] = pkbf(w2_w[n * 64 + k], w2_w[n * 64 + k + 1]);
            }
        }
    float b1v[4], b2v[4];
    #pragma unroll
    for (int nt = 0; nt < 4; ++nt) {
        b1v[nt] = w1_b[nt * 16 + l15];
        b2v[nt] = w2_b[nt * 16 + l15];
    }

    // prologue: prefetch first graph's A into registers
    float pf[6];
    {
        int g0 = blockIdx.x < num_graphs ? blockIdx.x : 0;
        const float* Ag = conn + (size_t)g0 * (GN * GN);
        #pragma unroll
        for (int i = 0; i < 6; ++i) {
            int e = t + 64 * i;
            if (e < GN * GN) pf[i] = Ag[e];
        }
    }

    #pragma unroll 1
    for (int g = blockIdx.x; g < num_graphs; g += gridDim.x) {
        // zero A region: rows 0..31, cols 0..31 (stride 68)
        #pragma unroll
        for (int i = 0; i < 4; ++i) {
            int s = t + 64 * i;          // 256 float4 slots
            int row = s >> 3, c4 = s & 7;
            f4 z = {0.f, 0.f, 0.f, 0.f};
            *(f4*)&S[row * 68 + c4 * 4] = z;
        }
        LWAIT();   // zeros before scatter (same addresses)
        // scatter prefetched A (361 floats)
        #pragma unroll
        for (int i = 0; i < 6; ++i) {
            if (t + 64 * i < GN * GN) S[rr[i] * 68 + cc[i]] = pf[i];
        }
        // issue prefetch for the NEXT graph (stays in flight all pipeline)
        {
            int gn = g + gridDim.x;
            const float* Ag = conn + (size_t)(gn < num_graphs ? gn : g) * (GN * GN);
            #pragma unroll
            for (int i = 0; i < 6; ++i) {
                int e = t + 64 * i;
                if (e < GN * GN) pf[i] = Ag[e];
            }
        }
        LWAIT();   // staging visible

        // degree -> dis (lanes 0..18), zero pad 19..31
        if (t < 32) {
            float dv = 0.f;
            if (t < GN) {
                float d = 1.0f;   // self loop
                #pragma unroll
                for (int c4 = 0; c4 < 8; ++c4) {
                    f4 v = *(f4*)&S[t * 68 + c4 * 4];
                    d += v.x + v.y + v.z + v.w;
                }
                dv = rsqrtf(d);
            }
            dis[t] = dv;
        }
        LWAIT();

        // pack aF (raw A) and anF (normalized adjacency), 2 M-tiles
        float dk[8];
        {
            f4 v0 = *(f4*)&dis[quad * 8];
            f4 v1 = *(f4*)&dis[quad * 8 + 4];
            dk[0]=v0.x; dk[1]=v0.y; dk[2]=v0.z; dk[3]=v0.w;
            dk[4]=v1.x; dk[5]=v1.y; dk[6]=v1.z; dk[7]=v1.w;
        }
        Frag aF[2], anF[2];
        #pragma unroll
        for (int mt = 0; mt < 2; ++mt) {
            int m = l15 + 16 * mt;
            float dm = dis[m];
            f4 v0 = *(f4*)&S[m * 68 + quad * 8];
            f4 v1 = *(f4*)&S[m * 68 + quad * 8 + 4];
            float av[8] = {v0.x, v0.y, v0.z, v0.w, v1.x, v1.y, v1.z, v1.w};
            float an[8];
            #pragma unroll
            for (int j = 0; j < 8; ++j) {
                int k = quad * 8 + j;
                an[j] = (av[j] + (m == k ? 1.f : 0.f)) * dm * dk[j];
            }
            #pragma unroll
            for (int p = 0; p < 4; ++p) {
                aF[mt].i[p]  = pkbf(av[2*p], av[2*p+1]);
                anF[mt].i[p] = pkbf(an[2*p], an[2*p+1]);
            }
        }
        LWAIT();   // A reads done before H1^T overwrites S

        // MFMA1: H1 = A @ W1^T + b1  -> S transposed (S[n*36 + k])
        #pragma unroll
        for (int mt = 0; mt < 2; ++mt)
            #pragma unroll
            for (int nt = 0; nt < 4; ++nt) {
                float bb = b1v[nt];
                f4 c = {bb, bb, bb, bb};
                c = __builtin_amdgcn_mfma_f32_16x16x32_bf16(aF[mt].s, w1F[nt].s, c, 0, 0, 0);
                int col = nt * 16 + l15;
                #pragma unroll
                for (int r = 0; r < 4; ++r)
                    S[col * 36 + (mt * 16 + quad * 4 + r)] = c[r];
            }
        LWAIT();

        // pack H1 as B-op: 2 x b128 per n-tile, mask k>=19
        Frag hF[4];
        #pragma unroll
        for (int nt = 0; nt < 4; ++nt) {
            int n = nt * 16 + l15;
            f4 v0 = *(f4*)&S[n * 36 + quad * 8];
            f4 v1 = *(f4*)&S[n * 36 + quad * 8 + 4];
            float vv[8] = {v0.x, v0.y, v0.z, v0.w, v1.x, v1.y, v1.z, v1.w};
            #pragma unroll
            for (int p = 0; p < 4; ++p)
                hF[nt].i[p] = pkbf(vv[2*p] * km[2*p], vv[2*p+1] * km[2*p+1]);
        }
        LWAIT();   // H1^T reads done

        // MFMA2: X1 = relu(An @ H1) -> S row-major (rows>=19 naturally zero)
        #pragma unroll
        for (int mt = 0; mt < 2; ++mt)
            #pragma unroll
            for (int nt = 0; nt < 4; ++nt) {
                f4 c = {0.f, 0.f, 0.f, 0.f};
                c = __builtin_amdgcn_mfma_f32_16x16x32_bf16(anF[mt].s, hF[nt].s, c, 0, 0, 0);
                int col = nt * 16 + l15;
                #pragma unroll
                for (int r = 0; r < 4; ++r)
                    S[(mt * 16 + quad * 4 + r) * 68 + col] = fmaxf(c[r], 0.f);
            }
        LWAIT();

        // pack X1 as A-op (2 b128 per (mt,kt))
        Frag xF[2][2];
        #pragma unroll
        for (int mt = 0; mt < 2; ++mt) {
            int m = l15 + 16 * mt;
            #pragma unroll
            for (int kt = 0; kt < 2; ++kt) {
                f4 v0 = *(f4*)&S[m * 68 + kt * 32 + quad * 8];
                f4 v1 = *(f4*)&S[m * 68 + kt * 32 + quad * 8 + 4];
                xF[mt][kt].i[0] = pkbf(v0.x, v0.y);
                xF[mt][kt].i[1] = pkbf(v0.z, v0.w);
                xF[mt][kt].i[2] = pkbf(v1.x, v1.y);
                xF[mt][kt].i[3] = pkbf(v1.z, v1.w);
            }
        }
        LWAIT();   // X1 reads done

        // MFMA3: H2 = X1 @ W2^T + b2 -> S transposed
        #pragma unroll
        for (int mt = 0; mt < 2; ++mt)
            #pragma unroll
            for (int nt = 0; nt < 4; ++nt) {
                float bb = b2v[nt];
                f4 c = {bb, bb, bb, bb};
                c = __builtin_amdgcn_mfma_f32_16x16x32_bf16(xF[mt][0].s, w2F[0][nt].s, c, 0, 0, 0);
                c = __builtin_amdgcn_mfma_f32_16x16x32_bf16(xF[mt][1].s, w2F[1][nt].s, c, 0, 0, 0);
                int col = nt * 16 + l15;
                #pragma unroll
                for (int r = 0; r < 4; ++r)
                    S[col * 36 + (mt * 16 + quad * 4 + r)] = c[r];
            }
        LWAIT();

        // pack H2 as B-op
        #pragma unroll
        for (int nt = 0; nt < 4; ++nt) {
            int n = nt * 16 + l15;
            f4 v0 = *(f4*)&S[n * 36 + quad * 8];
            f4 v1 = *(f4*)&S[n * 36 + quad * 8 + 4];
            float vv[8] = {v0.x, v0.y, v0.z, v0.w, v1.x, v1.y, v1.z, v1.w};
            #pragma unroll
            for (int p = 0; p < 4; ++p)
                hF[nt].i[p] = pkbf(vv[2*p] * km[2*p], vv[2*p+1] * km[2*p+1]);
        }

        // MFMA4: X2 = relu(An @ H2); column sums -> emb mean
        float cs[4];
        #pragma unroll
        for (int nt = 0; nt < 4; ++nt) cs[nt] = 0.f;
        #pragma unroll
        for (int mt = 0; mt < 2; ++mt)
            #pragma unroll
            for (int nt = 0; nt < 4; ++nt) {
                f4 c = {0.f, 0.f, 0.f, 0.f};
                c = __builtin_amdgcn_mfma_f32_16x16x32_bf16(anF[mt].s, hF[nt].s, c, 0, 0, 0);
                if (mt == 0) {
                    cs[nt] += fmaxf(c[0], 0.f) + fmaxf(c[1], 0.f)
                            + fmaxf(c[2], 0.f) + fmaxf(c[3], 0.f);
                } else if (quad == 0) {   // rows 16,17,18 valid
                    cs[nt] += fmaxf(c[0], 0.f) + fmaxf(c[1], 0.f) + fmaxf(c[2], 0.f);
                }
            }
        #pragma unroll
        for (int nt = 0; nt < 4; ++nt)
            ps[quad * 64 + nt * 16 + l15] = cs[nt];
        LWAIT();
        float tot = ps[t] + ps[64 + t] + ps[128 + t] + ps[192 + t];
        float mf = (float)mask[g];
        emb[(size_t)g * 64 + t] = tot * (1.f / 19.f) * mf;
        LWAIT();   // ps reads done before next iteration reuses LDS
    }
}

// ---------------------------------------------------------------------------
// Kernel B: LSTM layer 0, split-K.  512 threads = 8 waves per batch element
// => 2 waves/SIMD (R4 had 1: every stall was exposed).  Thread (r = tid&255,
// s = tid>>8) computes the s-th 32-wide half of gate-row r's dot product;
// halves meet in LDS (gs[row*2+s]) and the gate consumer adds b64 pairs.
// s is wave-uniform so readlane indices stay legal.  Raw s_barrier (no
// vmcnt drain); x-row loads issued at step top, consumed at step end
// (NAMED register buffer -- R6's dynamic-index scratch disaster reverted).
// ---------------------------------------------------------------------------
__global__ __launch_bounds__(512, 2) void lstm_l0(
    const float* __restrict__ x,      // (B*T, 64)
    const float* __restrict__ Wih, const float* __restrict__ Whh,
    const float* __restrict__ bih, const float* __restrict__ bhh,
    float* __restrict__ hseq)         // (B*T, 64)
{
    __shared__ __align__(16) float gs[2][512];
    const int tid = threadIdx.x;
    const int r = tid & 255;          // gate row
    const int s = tid >> 8;           // K-half (wave-uniform)
    const int l = tid & 63;           // h-dim lane
    const int b = blockIdx.x;
    const int so = s * 32;

    float wi[32], wh[32];
    {
        const float4* p = (const float4*)(Wih + r * 64 + so);
        const float4* q = (const float4*)(Whh + r * 64 + so);
        #pragma unroll
        for (int j = 0; j < 8; ++j) {
            ((float4*)wi)[j] = p[j];
            ((float4*)wh)[j] = q[j];
        }
    }
    const float bias = (s == 0) ? (bih[r] + bhh[r]) : 0.f;
    const float* __restrict__ xb = x + (size_t)b * TT * 64 + so;  // half-row base

    // x-contribution (this half) for step 0
    float xc;
    {
        float n0 = 0.f, n1 = 0.f, n2 = 0.f, n3 = 0.f;
        #pragma unroll
        for (int j = 0; j < 32; j += 4) {
            n0 = fmaf(xb[j],     wi[j],     n0);
            n1 = fmaf(xb[j + 1], wi[j + 1], n1);
            n2 = fmaf(xb[j + 2], wi[j + 2], n2);
            n3 = fmaf(xb[j + 3], wi[j + 3], n3);
        }
        xc = (n0 + n1) + (n2 + n3);
    }

    float h = 0.f, c = 0.f;

    #pragma unroll 1
    for (int t = 0; t < TT; ++t) {
        // issue raw loads of half-row t+1 NOW (consumed at iteration end)
        const f4* __restrict__ ern = (const f4*)(xb + (t + 1 < TT ? t + 1 : TT - 1) * 64);
        f4 xr0 = ern[0], xr1 = ern[1], xr2 = ern[2], xr3 = ern[3],
           xr4 = ern[4], xr5 = ern[5], xr6 = ern[6], xr7 = ern[7];

        // h-part half-dot (recurrent critical path)
        float a0 = bias + xc, a1 = 0.f, a2 = 0.f, a3 = 0.f;
        #pragma unroll
        for (int j = 0; j < 32; j += 4) {
            a0 = fmaf(rl(h, so + j),     wh[j],     a0);
            a1 = fmaf(rl(h, so + j + 1), wh[j + 1], a1);
            a2 = fmaf(rl(h, so + j + 2), wh[j + 2], a2);
            a3 = fmaf(rl(h, so + j + 3), wh[j + 3], a3);
        }
        gs[t & 1][(r << 1) | s] = (a0 + a1) + (a2 + a3);
        WGBAR();

        // gate partial pairs: 4 x b64 + adds
        const float* gp = gs[t & 1];
        float2 vi = *(const float2*)&gp[l * 2];
        float2 vf = *(const float2*)&gp[(64 + l) * 2];
        float2 vg = *(const float2*)&gp[(128 + l) * 2];
        float2 vo = *(const float2*)&gp[(192 + l) * 2];
        float gi = vi.x + vi.y, gf = vf.x + vf.y;
        float gg = vg.x + vg.y, go = vo.x + vo.y;

        // x-FMAs for step t+1 (independent; hide ds_read/act latency)
        float n0 = 0.f, n1 = 0.f, n2 = 0.f, n3 = 0.f;
        n0 = fmaf(xr0.x, wi[0],  n0); n1 = fmaf(xr0.y, wi[1],  n1);
        n2 = fmaf(xr0.z, wi[2],  n2); n3 = fmaf(xr0.w, wi[3],  n3);
        n0 = fmaf(xr1.x, wi[4],  n0); n1 = fmaf(xr1.y, wi[5],  n1);
        n2 = fmaf(xr1.z, wi[6],  n2); n3 = fmaf(xr1.w, wi[7],  n3);
        n0 = fmaf(xr2.x, wi[8],  n0); n1 = fmaf(xr2.y, wi[9],  n1);
        n2 = fmaf(xr2.z, wi[10], n2); n3 = fmaf(xr2.w, wi[11], n3);
        n0 = fmaf(xr3.x, wi[12], n0); n1 = fmaf(xr3.y, wi[13], n1);
        n2 = fmaf(xr3.z, wi[14], n2); n3 = fmaf(xr3.w, wi[15], n3);
        n0 = fmaf(xr4.x, wi[16], n0); n1 = fmaf(xr4.y, wi[17], n1);
        n2 = fmaf(xr4.z, wi[18], n2); n3 = fmaf(xr4.w, wi[19], n3);
        n0 = fmaf(xr5.x, wi[20], n0); n1 = fmaf(xr5.y, wi[21], n1);
        n2 = fmaf(xr5.z, wi[22], n2); n3 = fmaf(xr5.w, wi[23], n3);
        n0 = fmaf(xr6.x, wi[24], n0); n1 = fmaf(xr6.y, wi[25], n1);
        n2 = fmaf(xr6.z, wi[26], n2); n3 = fmaf(xr6.w, wi[27], n3);
        n0 = fmaf(xr7.x, wi[28], n0); n1 = fmaf(xr7.y, wi[29], n1);
        n2 = fmaf(xr7.z, wi[30], n2); n3 = fmaf(xr7.w, wi[31], n3);
        float xcn = (n0 + n1) + (n2 + n3);

        // activations (step t) -- identical in all 8 waves
        c = sigm(gf) * c + sigm(gi) * tanha(gg);
        h = sigm(go) * tanha(c);
        if (tid < 64) hseq[((size_t)b * TT + t) * 64 + l] = h;
        xc = xcn;
    }
}

// ---------------------------------------------------------------------------
// Kernel C: LSTM layer 1 + FC head, same split-K structure.
// ---------------------------------------------------------------------------
__global__ __launch_bounds__(512, 2) void lstm_l1_head(
    const float* __restrict__ x,      // (B*T, 64) = h0seq
    const int*   __restrict__ mask,   // (B, T)
    const float* __restrict__ Wih, const float* __restrict__ Whh,
    const float* __restrict__ bih, const float* __restrict__ bhh,
    const float* __restrict__ fc1_w, const float* __restrict__ fc1_b,
    const float* __restrict__ fc2_w, const float* __restrict__ fc2_b,
    float* __restrict__ out)          // (B, 2)
{
    __shared__ __align__(16) float gs[2][512];
    __shared__ int li_s;
    const int tid = threadIdx.x;
    const int r = tid & 255;
    const int s = tid >> 8;
    const int l = tid & 63;
    const int b = blockIdx.x;
    const int so = s * 32;

    float wi[32], wh[32];
    {
        const float4* p = (const float4*)(Wih + r * 64 + so);
        const float4* q = (const float4*)(Whh + r * 64 + so);
        #pragma unroll
        for (int j = 0; j < 8; ++j) {
            ((float4*)wi)[j] = p[j];
            ((float4*)wh)[j] = q[j];
        }
    }
    const float bias = (s == 0) ? (bih[r] + bhh[r]) : 0.f;

    // last_idx = clip(sum(mask)-1, 0, T-1)
    if (tid < 256) gs[0][tid] = (float)mask[b * TT + tid];
    __syncthreads();
    if (tid == 0) {
        float sm = 0.f;
        for (int t = 0; t < TT; ++t) sm += gs[0][t];
        int li = (int)sm - 1;
        li = li < 0 ? 0 : (li > TT - 1 ? TT - 1 : li);
        li_s = li;
    }
    __syncthreads();
    const int lastidx = li_s;

    const float* __restrict__ xb = x + (size_t)b * TT * 64 + so;

    float xc;
    {
        float n0 = 0.f, n1 = 0.f, n2 = 0.f, n3 = 0.f;
        #pragma unroll
        for (int j = 0; j < 32; j += 4) {
            n0 = fmaf(xb[j],     wi[j],     n0);
            n1 = fmaf(xb[j + 1], wi[j + 1], n1);
            n2 = fmaf(xb[j + 2], wi[j + 2], n2);
            n3 = fmaf(xb[j + 3], wi[j + 3], n3);
        }
        xc = (n0 + n1) + (n2 + n3);
    }

    float h = 0.f, c = 0.f, hl = 0.f;

    #pragma unroll 1
    for (int t = 0; t < TT; ++t) {
        const f4* __restrict__ ern = (const f4*)(xb + (t + 1 < TT ? t + 1 : TT - 1) * 64);
        f4 xr0 = ern[0], xr1 = ern[1], xr2 = ern[2], xr3 = ern[3],
           xr4 = ern[4], xr5 = ern[5], xr6 = ern[6], xr7 = ern[7];

        float a0 = bias + xc, a1 = 0.f, a2 = 0.f, a3 = 0.f;
        #pragma unroll
        for (int j = 0; j < 32; j += 4) {
            a0 = fmaf(rl(h, so + j),     wh[j],     a0);
            a1 = fmaf(rl(h, so + j + 1), wh[j + 1], a1);
            a2 = fmaf(rl(h, so + j + 2), wh[j + 2], a2);
            a3 = fmaf(rl(h, so + j + 3), wh[j + 3], a3);
        }
        gs[t & 1][(r << 1) | s] = (a0 + a1) + (a2 + a3);
        WGBAR();

        const float* gp = gs[t & 1];
        float2 vi = *(const float2*)&gp[l * 2];
        float2 vf = *(const float2*)&gp[(64 + l) * 2];
        float2 vg = *(const float2*)&gp[(128 + l) * 2];
        float2 vo = *(const float2*)&gp[(192 + l) * 2];
        float gi = vi.x + vi.y, gf = vf.x + vf.y;
        float gg = vg.x + vg.y, go = vo.x + vo.y;

        float n0 = 0.f, n1 = 0.f, n2 = 0.f, n3 = 0.f;
        n0 = fmaf(xr0.x, wi[0],  n0); n1 = fmaf(xr0.y, wi[1],  n1);
        n2 = fmaf(xr0.z, wi[2],  n2); n3 = fmaf(xr0.w, wi[3],  n3);
        n0 = fmaf(xr1.x, wi[4],  n0); n1 = fmaf(xr1.y, wi[5],  n1);
        n2 = fmaf(xr1.z, wi[6],  n2); n3 = fmaf(xr1.w, wi[7],  n3);
        n0 = fmaf(xr2.x, wi[8],  n0); n1 = fmaf(xr2.y, wi[9],  n1);
        n2 = fmaf(xr2.z, wi[10], n2); n3 = fmaf(xr2.w, wi[11], n3);
        n0 = fmaf(xr3.x, wi[12], n0); n1 = fmaf(xr3.y, wi[13], n1);
        n2 = fmaf(xr3.z, wi[14], n2); n3 = fmaf(xr3.w, wi[15], n3);
        n0 = fmaf(xr4.x, wi[16], n0); n1 = fmaf(xr4.y, wi[17], n1);
        n2 = fmaf(xr4.z, wi[18], n2); n3 = fmaf(xr4.w, wi[19], n3);
        n0 = fmaf(xr5.x, wi[20], n0); n1 = fmaf(xr5.y, wi[21], n1);
        n2 = fmaf(xr5.z, wi[22], n2); n3 = fmaf(xr5.w, wi[23], n3);
        n0 = fmaf(xr6.x, wi[24], n0); n1 = fmaf(xr6.y, wi[25], n1);
        n2 = fmaf(xr6.z, wi[26], n2); n3 = fmaf(xr6.w, wi[27], n3);
        n0 = fmaf(xr7.x, wi[28], n0); n1 = fmaf(xr7.y, wi[29], n1);
        n2 = fmaf(xr7.z, wi[30], n2); n3 = fmaf(xr7.w, wi[31], n3);
        float xcn = (n0 + n1) + (n2 + n3);

        c = sigm(gf) * c + sigm(gi) * tanha(gg);
        h = sigm(go) * tanha(c);
        if (t == lastidx) hl = h;
        xc = xcn;
    }

    // head: fc1 (64->32) relu, fc2 (32->2); wave 0 only
    __syncthreads();
    if (tid < 32) {
        float acc = fc1_b[l];
        const float* fw = fc1_w + l * 64;
        #pragma unroll
        for (int j = 0; j < 64; ++j)
            acc = fmaf(fw[j], rl(hl, j), acc);
        gs[0][l] = fmaxf(acc, 0.f);
    }
    __syncthreads();
    if (tid < 2) {
        float acc = fc2_b[l];
        #pragma unroll
        for (int j = 0; j < 32; ++j)
            acc = fmaf(fc2_w[l * 32 + j], gs[0][j], acc);
        out[b * 2 + l] = acc;
    }
}

// ---------------------------------------------------------------------------
extern "C" void kernel_launch(void* const* d_in, const int* in_sizes, int n_in,
                              void* d_out, int out_size, void* d_ws, size_t ws_size,
                              hipStream_t stream)
{
    const float* conn  = (const float*)d_in[0];
    const int*   mask  = (const int*)  d_in[1];
    const float* w1_w  = (const float*)d_in[2];
    const float* w1_b  = (const float*)d_in[3];
    const float* w2_w  = (const float*)d_in[4];
    const float* w2_b  = (const float*)d_in[5];
    const float* Wih0  = (const float*)d_in[6];
    const float* Whh0  = (const float*)d_in[7];
    const float* bih0  = (const float*)d_in[8];
    const float* bhh0  = (const float*)d_in[9];
    const float* Wih1  = (const float*)d_in[10];
    const float* Whh1  = (const float*)d_in[11];
    const float* bih1  = (const float*)d_in[12];
    const float* bhh1  = (const float*)d_in[13];
    const float* fc1_w = (const float*)d_in[14];
    const float* fc1_b = (const float*)d_in[15];
    const float* fc2_w = (const float*)d_in[16];
    const float* fc2_b = (const float*)d_in[17];

    float* out = (float*)d_out;
    float* emb   = (float*)d_ws;                         // 16.8 MB
    float* h0seq = (float*)d_ws + (size_t)BB * TT * 64;  // +16.8 MB

    const int num_graphs = BB * TT;

    encoder_mfma<<<8192, 64, 0, stream>>>(
        conn, mask, w1_w, w1_b, w2_w, w2_b, emb, num_graphs);

    lstm_l0<<<BB, 512, 0, stream>>>(emb, Wih0, Whh0, bih0, bhh0, h0seq);

    lstm_l1_head<<<BB, 512, 0, stream>>>(
        h0seq, mask, Wih1, Whh1, bih1, bhh1,
        fc1_w, fc1_b, fc2_w, fc2_b, out);
}

// Round 8
// 717.335 us; speedup vs baseline: 3.1096x; 1.0790x over previous
//
#include <hip/hip_runtime.h>
#include <hip/hip_bf16.h>
#include <math.h>

#define GN 19            // graph nodes
#define BB 256
#define TT 256

typedef short short8 __attribute__((ext_vector_type(8)));
typedef float f4 __attribute__((ext_vector_type(4)));

union Frag { int i[4]; short8 s; };

// wave-local LDS ordering fence: wait LDS ops, NO vmcnt drain, no barrier.
#define LWAIT() __asm__ volatile("s_waitcnt lgkmcnt(0)" ::: "memory")
// workgroup barrier WITHOUT vmcnt(0) drain: global loads/stores stay in flight.
#define WGBAR() __asm__ volatile("s_waitcnt lgkmcnt(0)\ns_barrier" ::: "memory")

// packed RNE float pair -> bf16 pair (v_cvt_pk_bf16_f32 on gfx950)
__device__ __forceinline__ int pkbf(float a, float b) {
    __hip_bfloat162 h2 = __float22bfloat162_rn(make_float2(a, b));
    union { __hip_bfloat162 h; int i; } u; u.h = h2; return u.i;
}

__device__ __forceinline__ float rl(float v, int j) {
    return __int_as_float(__builtin_amdgcn_readlane(__float_as_int(v), j));
}
__device__ __forceinline__ float fexp2(float x) { return __builtin_amdgcn_exp2f(x); }
__device__ __forceinline__ float frcp(float x)  { return __builtin_amdgcn_rcpf(x); }
__device__ __forceinline__ float sigm(float x)  { return frcp(1.f + fexp2(-1.4426950408889634f * x)); }
__device__ __forceinline__ float tanha(float x) { float e = fexp2(2.8853900817779268f * x); return 1.f - 2.f * frcp(e + 1.f); }

// ---------------------------------------------------------------------------
// Kernel A: graph encoder via bf16 MFMA (16x16x32).  One wave per block,
// grid-stride over graphs.  1-wave workgroup => no s_barrier needed at all;
// phase ordering via lgkmcnt waits only (global loads stay in flight).
// Next graph's A is register-prefetched during the current graph's pipeline.
// ---------------------------------------------------------------------------
__global__ __launch_bounds__(64) void encoder_mfma(
    const float* __restrict__ conn,   // (G,19,19)
    const int*   __restrict__ mask,   // (G)
    const float* __restrict__ w1_w,   // (64,19)
    const float* __restrict__ w1_b,   // (64)
    const float* __restrict__ w2_w,   // (64,64)
    const float* __restrict__ w2_b,   // (64)
    float* __restrict__ emb,          // (G,64)
    int num_graphs)
{
    __shared__ float S[2304];         // 9216 B, reused 4 ways
    __shared__ float dis[32];
    __shared__ float ps[256];

    const int t = threadIdx.x;
    const int l15 = t & 15;
    const int quad = t >> 4;

    // k-validity mask for B-operand repacks (k = quad*8+j < 19)
    float km[8];
    #pragma unroll
    for (int j = 0; j < 8; ++j) km[j] = (quad * 8 + j < GN) ? 1.f : 0.f;

    // loop-invariant scatter coords for A staging (e = t + 64*i)
    int rr[6], cc[6];
    #pragma unroll
    for (int i = 0; i < 6; ++i) {
        int e = t + 64 * i;
        rr[i] = e / GN;
        cc[i] = e - rr[i] * GN;
    }

    // ---- weight fragments + biases (once per block) ----
    Frag w1F[4];
    #pragma unroll
    for (int nt = 0; nt < 4; ++nt) {
        int n = nt * 16 + l15;
        #pragma unroll
        for (int p = 0; p < 4; ++p) {
            int k0 = quad * 8 + 2 * p, k1 = k0 + 1;
            float a = (k0 < GN) ? w1_w[n * GN + k0] : 0.f;
            float b = (k1 < GN) ? w1_w[n * GN + k1] : 0.f;
            w1F[nt].i[p] = pkbf(a, b);
        }
    }
    Frag w2F[2][4];
    #pragma unroll
    for (int kt = 0; kt < 2; ++kt)
        #pragma unroll
        for (int nt = 0; nt < 4; ++nt) {
            int n = nt * 16 + l15;
            #pragma unroll
            for (int p = 0; p < 4; ++p) {
                int k = kt * 32 + quad * 8 + 2 * p;
                w2F[kt][nt].i[p] = pkbf(w2_w[n * 64 + k], w2_w[n * 64 + k + 1]);
            }
        }
    float b1v[4], b2v[4];
    #pragma unroll
    for (int nt = 0; nt < 4; ++nt) {
        b1v[nt] = w1_b[nt * 16 + l15];
        b2v[nt] = w2_b[nt * 16 + l15];
    }

    // prologue: prefetch first graph's A into registers
    float pf[6];
    {
        int g0 = blockIdx.x < num_graphs ? blockIdx.x : 0;
        const float* Ag = conn + (size_t)g0 * (GN * GN);
        #pragma unroll
        for (int i = 0; i < 6; ++i) {
            int e = t + 64 * i;
            if (e < GN * GN) pf[i] = Ag[e];
        }
    }

    #pragma unroll 1
    for (int g = blockIdx.x; g < num_graphs; g += gridDim.x) {
        // zero A region: rows 0..31, cols 0..31 (stride 68)
        #pragma unroll
        for (int i = 0; i < 4; ++i) {
            int s = t + 64 * i;          // 256 float4 slots
            int row = s >> 3, c4 = s & 7;
            f4 z = {0.f, 0.f, 0.f, 0.f};
            *(f4*)&S[row * 68 + c4 * 4] = z;
        }
        LWAIT();   // zeros before scatter (same addresses)
        // scatter prefetched A (361 floats)
        #pragma unroll
        for (int i = 0; i < 6; ++i) {
            if (t + 64 * i < GN * GN) S[rr[i] * 68 + cc[i]] = pf[i];
        }
        // issue prefetch for the NEXT graph (stays in flight all pipeline)
        {
            int gn = g + gridDim.x;
            const float* Ag = conn + (size_t)(gn < num_graphs ? gn : g) * (GN * GN);
            #pragma unroll
            for (int i = 0; i < 6; ++i) {
                int e = t + 64 * i;
                if (e < GN * GN) pf[i] = Ag[e];
            }
        }
        LWAIT();   // staging visible

        // degree -> dis (lanes 0..18), zero pad 19..31
        if (t < 32) {
            float dv = 0.f;
            if (t < GN) {
                float d = 1.0f;   // self loop
                #pragma unroll
                for (int c4 = 0; c4 < 8; ++c4) {
                    f4 v = *(f4*)&S[t * 68 + c4 * 4];
                    d += v.x + v.y + v.z + v.w;
                }
                dv = rsqrtf(d);
            }
            dis[t] = dv;
        }
        LWAIT();

        // pack aF (raw A) and anF (normalized adjacency), 2 M-tiles
        float dk[8];
        {
            f4 v0 = *(f4*)&dis[quad * 8];
            f4 v1 = *(f4*)&dis[quad * 8 + 4];
            dk[0]=v0.x; dk[1]=v0.y; dk[2]=v0.z; dk[3]=v0.w;
            dk[4]=v1.x; dk[5]=v1.y; dk[6]=v1.z; dk[7]=v1.w;
        }
        Frag aF[2], anF[2];
        #pragma unroll
        for (int mt = 0; mt < 2; ++mt) {
            int m = l15 + 16 * mt;
            float dm = dis[m];
            f4 v0 = *(f4*)&S[m * 68 + quad * 8];
            f4 v1 = *(f4*)&S[m * 68 + quad * 8 + 4];
            float av[8] = {v0.x, v0.y, v0.z, v0.w, v1.x, v1.y, v1.z, v1.w};
            float an[8];
            #pragma unroll
            for (int j = 0; j < 8; ++j) {
                int k = quad * 8 + j;
                an[j] = (av[j] + (m == k ? 1.f : 0.f)) * dm * dk[j];
            }
            #pragma unroll
            for (int p = 0; p < 4; ++p) {
                aF[mt].i[p]  = pkbf(av[2*p], av[2*p+1]);
                anF[mt].i[p] = pkbf(an[2*p], an[2*p+1]);
            }
        }
        LWAIT();   // A reads done before H1^T overwrites S

        // MFMA1: H1 = A @ W1^T + b1  -> S transposed (S[n*36 + k])
        #pragma unroll
        for (int mt = 0; mt < 2; ++mt)
            #pragma unroll
            for (int nt = 0; nt < 4; ++nt) {
                float bb = b1v[nt];
                f4 c = {bb, bb, bb, bb};
                c = __builtin_amdgcn_mfma_f32_16x16x32_bf16(aF[mt].s, w1F[nt].s, c, 0, 0, 0);
                int col = nt * 16 + l15;
                #pragma unroll
                for (int r = 0; r < 4; ++r)
                    S[col * 36 + (mt * 16 + quad * 4 + r)] = c[r];
            }
        LWAIT();

        // pack H1 as B-op: 2 x b128 per n-tile, mask k>=19
        Frag hF[4];
        #pragma unroll
        for (int nt = 0; nt < 4; ++nt) {
            int n = nt * 16 + l15;
            f4 v0 = *(f4*)&S[n * 36 + quad * 8];
            f4 v1 = *(f4*)&S[n * 36 + quad * 8 + 4];
            float vv[8] = {v0.x, v0.y, v0.z, v0.w, v1.x, v1.y, v1.z, v1.w};
            #pragma unroll
            for (int p = 0; p < 4; ++p)
                hF[nt].i[p] = pkbf(vv[2*p] * km[2*p], vv[2*p+1] * km[2*p+1]);
        }
        LWAIT();   // H1^T reads done

        // MFMA2: X1 = relu(An @ H1) -> S row-major (rows>=19 naturally zero)
        #pragma unroll
        for (int mt = 0; mt < 2; ++mt)
            #pragma unroll
            for (int nt = 0; nt < 4; ++nt) {
                f4 c = {0.f, 0.f, 0.f, 0.f};
                c = __builtin_amdgcn_mfma_f32_16x16x32_bf16(anF[mt].s, hF[nt].s, c, 0, 0, 0);
                int col = nt * 16 + l15;
                #pragma unroll
                for (int r = 0; r < 4; ++r)
                    S[(mt * 16 + quad * 4 + r) * 68 + col] = fmaxf(c[r], 0.f);
            }
        LWAIT();

        // pack X1 as A-op (2 b128 per (mt,kt))
        Frag xF[2][2];
        #pragma unroll
        for (int mt = 0; mt < 2; ++mt) {
            int m = l15 + 16 * mt;
            #pragma unroll
            for (int kt = 0; kt < 2; ++kt) {
                f4 v0 = *(f4*)&S[m * 68 + kt * 32 + quad * 8];
                f4 v1 = *(f4*)&S[m * 68 + kt * 32 + quad * 8 + 4];
                xF[mt][kt].i[0] = pkbf(v0.x, v0.y);
                xF[mt][kt].i[1] = pkbf(v0.z, v0.w);
                xF[mt][kt].i[2] = pkbf(v1.x, v1.y);
                xF[mt][kt].i[3] = pkbf(v1.z, v1.w);
            }
        }
        LWAIT();   // X1 reads done

        // MFMA3: H2 = X1 @ W2^T + b2 -> S transposed
        #pragma unroll
        for (int mt = 0; mt < 2; ++mt)
            #pragma unroll
            for (int nt = 0; nt < 4; ++nt) {
                float bb = b2v[nt];
                f4 c = {bb, bb, bb, bb};
                c = __builtin_amdgcn_mfma_f32_16x16x32_bf16(xF[mt][0].s, w2F[0][nt].s, c, 0, 0, 0);
                c = __builtin_amdgcn_mfma_f32_16x16x32_bf16(xF[mt][1].s, w2F[1][nt].s, c, 0, 0, 0);
                int col = nt * 16 + l15;
                #pragma unroll
                for (int r = 0; r < 4; ++r)
                    S[col * 36 + (mt * 16 + quad * 4 + r)] = c[r];
            }
        LWAIT();

        // pack H2 as B-op
        #pragma unroll
        for (int nt = 0; nt < 4; ++nt) {
            int n = nt * 16 + l15;
            f4 v0 = *(f4*)&S[n * 36 + quad * 8];
            f4 v1 = *(f4*)&S[n * 36 + quad * 8 + 4];
            float vv[8] = {v0.x, v0.y, v0.z, v0.w, v1.x, v1.y, v1.z, v1.w};
            #pragma unroll
            for (int p = 0; p < 4; ++p)
                hF[nt].i[p] = pkbf(vv[2*p] * km[2*p], vv[2*p+1] * km[2*p+1]);
        }

        // MFMA4: X2 = relu(An @ H2); column sums -> emb mean
        float cs[4];
        #pragma unroll
        for (int nt = 0; nt < 4; ++nt) cs[nt] = 0.f;
        #pragma unroll
        for (int mt = 0; mt < 2; ++mt)
            #pragma unroll
            for (int nt = 0; nt < 4; ++nt) {
                f4 c = {0.f, 0.f, 0.f, 0.f};
                c = __builtin_amdgcn_mfma_f32_16x16x32_bf16(anF[mt].s, hF[nt].s, c, 0, 0, 0);
                if (mt == 0) {
                    cs[nt] += fmaxf(c[0], 0.f) + fmaxf(c[1], 0.f)
                            + fmaxf(c[2], 0.f) + fmaxf(c[3], 0.f);
                } else if (quad == 0) {   // rows 16,17,18 valid
                    cs[nt] += fmaxf(c[0], 0.f) + fmaxf(c[1], 0.f) + fmaxf(c[2], 0.f);
                }
            }
        #pragma unroll
        for (int nt = 0; nt < 4; ++nt)
            ps[quad * 64 + nt * 16 + l15] = cs[nt];
        LWAIT();
        float tot = ps[t] + ps[64 + t] + ps[128 + t] + ps[192 + t];
        float mf = (float)mask[g];
        emb[(size_t)g * 64 + t] = tot * (1.f / 19.f) * mf;
        LWAIT();   // ps reads done before next iteration reuses LDS
    }
}

// ---------------------------------------------------------------------------
// Kernel B: FUSED 2-layer LSTM + head, fused BY WAVES (not by threads -- R5's
// per-thread fusion blew the register file).  512 threads per batch element:
// waves 0-3 run layer 0 (thread = gate row tid), waves 4-7 run layer 1
// (gate row tid-256), with a 1-step skew.  Each thread loads only ITS layer's
// weight row (selected pointer -> same wi/wh arrays; per-thread regs = R4).
// Each SIMD hosts one l0-wave + one l1-wave: barrier / ds_read / act stalls
// are shared by two layers.  h0 crosses layers via a 64-float LDS double
// buffer; l1 consumes it with 1 ds_read_b32 + readlane-dot.  2 no-drain
// barriers per iteration (same total as the two split kernels had).
// h0seq never touches HBM.
// ---------------------------------------------------------------------------
__global__ __launch_bounds__(512, 2) void lstm_fused2(
    const float* __restrict__ x,      // (B*T, 64) = emb
    const int*   __restrict__ mask,   // (B, T)
    const float* __restrict__ Wih0, const float* __restrict__ Whh0,
    const float* __restrict__ bih0, const float* __restrict__ bhh0,
    const float* __restrict__ Wih1, const float* __restrict__ Whh1,
    const float* __restrict__ bih1, const float* __restrict__ bhh1,
    const float* __restrict__ fc1_w, const float* __restrict__ fc1_b,
    const float* __restrict__ fc2_w, const float* __restrict__ fc2_b,
    float* __restrict__ out)          // (B, 2)
{
    __shared__ __align__(16) float gs[2][512];
    __shared__ float h0buf[2][64];
    __shared__ int li_s;
    const int tid = threadIdx.x;
    const bool isL0 = tid < 256;
    const int r = tid & 255;          // gate row within layer
    const int l = tid & 63;           // h-dim lane
    const int gbase = tid & 256;      // layer's gs region base
    const int b = blockIdx.x;

    // select THIS thread's layer weights (one set per thread -- R4 budget)
    const float* Wih = isL0 ? Wih0 : Wih1;
    const float* Whh = isL0 ? Whh0 : Whh1;
    const float* bih = isL0 ? bih0 : bih1;
    const float* bhh = isL0 ? bhh0 : bhh1;

    float wi[64], wh[64];
    {
        const float4* p = (const float4*)(Wih + r * 64);
        const float4* q = (const float4*)(Whh + r * 64);
        #pragma unroll
        for (int j = 0; j < 16; ++j) {
            ((float4*)wi)[j] = p[j];
            ((float4*)wh)[j] = q[j];
        }
    }
    const float bias = bih[r] + bhh[r];

    // last_idx = clip(sum(mask)-1, 0, T-1)
    if (tid < 256) gs[0][tid] = (float)mask[b * TT + tid];
    __syncthreads();
    if (tid == 0) {
        float sm = 0.f;
        for (int t = 0; t < TT; ++t) sm += gs[0][t];
        int li = (int)sm - 1;
        li = li < 0 ? 0 : (li > TT - 1 ? TT - 1 : li);
        li_s = li;
    }
    __syncthreads();
    const int lastidx = li_s;

    const float* __restrict__ xb = x + (size_t)b * TT * 64;

    // l0 prologue: x-contribution for step 0 (uniform s_loads)
    float xc = 0.f;
    if (isL0) {
        float n0 = 0.f, n1 = 0.f, n2 = 0.f, n3 = 0.f;
        #pragma unroll
        for (int j = 0; j < 64; j += 4) {
            n0 = fmaf(xb[j],     wi[j],     n0);
            n1 = fmaf(xb[j + 1], wi[j + 1], n1);
            n2 = fmaf(xb[j + 2], wi[j + 2], n2);
            n3 = fmaf(xb[j + 3], wi[j + 3], n3);
        }
        xc = (n0 + n1) + (n2 + n3);
    }

    float h = 0.f, c = 0.f, hl = 0.f;

    #pragma unroll 1
    for (int t = 0; t <= TT; ++t) {
        const bool a0 = isL0 && (t < TT);     // layer 0 computes step t
        const bool a1 = !isL0 && (t >= 1);    // layer 1 computes step t-1

        // ---- phase A: gate FMAs ----
        f4 xr[16];                            // l0 only (const-indexed)
        if (a0) {
            const f4* __restrict__ rp =
                (const f4*)(xb + (t + 1 < TT ? t + 1 : TT - 1) * 64);
            #pragma unroll
            for (int k = 0; k < 16; ++k) xr[k] = rp[k];
        }
        float h0r = 0.f;
        if (a1) h0r = h0buf[(t + 1) & 1][l];  // h0[t-1] ((t-1)&1 == (t+1)&1)

        if (a0 || a1) {
            float s0 = bias, s1 = 0.f, s2 = 0.f, s3 = 0.f;
            if (a0) s0 += xc;
            #pragma unroll
            for (int j = 0; j < 64; j += 4) {   // recurrent dot (own h)
                s0 = fmaf(rl(h, j),     wh[j],     s0);
                s1 = fmaf(rl(h, j + 1), wh[j + 1], s1);
                s2 = fmaf(rl(h, j + 2), wh[j + 2], s2);
                s3 = fmaf(rl(h, j + 3), wh[j + 3], s3);
            }
            if (a1) {                            // l1 x-dot over h0[t-1]
                #pragma unroll
                for (int j = 0; j < 64; j += 4) {
                    s0 = fmaf(rl(h0r, j),     wi[j],     s0);
                    s1 = fmaf(rl(h0r, j + 1), wi[j + 1], s1);
                    s2 = fmaf(rl(h0r, j + 2), wi[j + 2], s2);
                    s3 = fmaf(rl(h0r, j + 3), wi[j + 3], s3);
                }
            }
            gs[t & 1][tid] = (s0 + s1) + (s2 + s3);
        }
        WGBAR();   // barrier 1: gs writes -> gs reads

        // ---- phase B: gate exchange + activations ----
        if (a0 || a1) {
            const float* gp = gs[t & 1] + gbase;
            float gi = gp[l], gf = gp[64 + l], gg = gp[128 + l], go = gp[192 + l];

            float xcn = 0.f;
            if (a0) {   // x-FMAs for step t+1 fill the ds_read latency window
                float n0 = 0.f, n1 = 0.f, n2 = 0.f, n3 = 0.f;
                #pragma unroll
                for (int k = 0; k < 16; ++k) {
                    f4 v = xr[k];
                    n0 = fmaf(v.x, wi[4*k],     n0);
                    n1 = fmaf(v.y, wi[4*k + 1], n1);
                    n2 = fmaf(v.z, wi[4*k + 2], n2);
                    n3 = fmaf(v.w, wi[4*k + 3], n3);
                }
                xcn = (n0 + n1) + (n2 + n3);
            }

            c = sigm(gf) * c + sigm(gi) * tanha(gg);
            h = sigm(go) * tanha(c);
            if (a0) {
                if (tid < 64) h0buf[t & 1][l] = h;   // publish h0[t]
                xc = xcn;
            }
            if (a1 && (t - 1 == lastidx)) hl = h;
        }
        WGBAR();   // barrier 2: h0buf write -> next iteration's read
    }

    // head: fc1 (64->32) relu, fc2 (32->2); wave 4 (layer-1 wave 0) only
    __syncthreads();
    if (tid >= 256 && tid < 288) {
        float acc = fc1_b[l];
        const float* fw = fc1_w + l * 64;
        #pragma unroll
        for (int j = 0; j < 64; ++j)
            acc = fmaf(fw[j], rl(hl, j), acc);
        gs[0][l] = fmaxf(acc, 0.f);
    }
    __syncthreads();
    if (tid >= 256 && tid < 258) {
        int o = tid - 256;
        float acc = fc2_b[o];
        #pragma unroll
        for (int j = 0; j < 32; ++j)
            acc = fmaf(fc2_w[o * 32 + j], gs[0][j], acc);
        out[b * 2 + o] = acc;
    }
}

// ---------------------------------------------------------------------------
extern "C" void kernel_launch(void* const* d_in, const int* in_sizes, int n_in,
                              void* d_out, int out_size, void* d_ws, size_t ws_size,
                              hipStream_t stream)
{
    const float* conn  = (const float*)d_in[0];
    const int*   mask  = (const int*)  d_in[1];
    const float* w1_w  = (const float*)d_in[2];
    const float* w1_b  = (const float*)d_in[3];
    const float* w2_w  = (const float*)d_in[4];
    const float* w2_b  = (const float*)d_in[5];
    const float* Wih0  = (const float*)d_in[6];
    const float* Whh0  = (const float*)d_in[7];
    const float* bih0  = (const float*)d_in[8];
    const float* bhh0  = (const float*)d_in[9];
    const float* Wih1  = (const float*)d_in[10];
    const float* Whh1  = (const float*)d_in[11];
    const float* bih1  = (const float*)d_in[12];
    const float* bhh1  = (const float*)d_in[13];
    const float* fc1_w = (const float*)d_in[14];
    const float* fc1_b = (const float*)d_in[15];
    const float* fc2_w = (const float*)d_in[16];
    const float* fc2_b = (const float*)d_in[17];

    float* out = (float*)d_out;
    float* emb = (float*)d_ws;            // 16.8 MB

    const int num_graphs = BB * TT;

    encoder_mfma<<<8192, 64, 0, stream>>>(
        conn, mask, w1_w, w1_b, w2_w, w2_b, emb, num_graphs);

    lstm_fused2<<<BB, 512, 0, stream>>>(
        emb, mask, Wih0, Whh0, bih0, bhh0, Wih1, Whh1, bih1, bhh1,
        fc1_w, fc1_b, fc2_w, fc2_b, out);
}